// Round 5
// baseline (957.174 us; speedup 1.0000x reference)
//
#include <hip/hip_runtime.h>
#include <cstdint>
#include <cstddef>

// ---------------- constants ----------------
#define N_TOK   16384      // 4 * 4096
#define D_TOTAL 2048
#define N_HEAD  16
#define D_HEAD  128
#define HID     512
#define MT      128        // tokens per block (two 64-token halves)
#define HT      64         // tokens per half
#define RMS_EPS 1.1920929e-07f   // np.finfo(np.float32).eps

typedef __attribute__((ext_vector_type(8)))  short  short8;
typedef __attribute__((ext_vector_type(4)))  float  float4_t;
typedef __attribute__((ext_vector_type(16))) float  f32x16;
typedef __attribute__((ext_vector_type(2)))  unsigned int uint2_t;

// ---------------- bf16 helpers ----------------
__device__ __forceinline__ unsigned short f2bf(float f) {
    union { float f; unsigned int i; } v; v.f = f;
    unsigned int b = v.i;
    b += 0x7FFFu + ((b >> 16) & 1u);      // round-to-nearest-even
    return (unsigned short)(b >> 16);
}

// packed fp32x2 -> bf16x2 (RNE, same rounding as f2bf); no builtin on gfx950
__device__ __forceinline__ unsigned int cvt_pk_bf16(float lo, float hi) {
    unsigned int r;
    asm("v_cvt_pk_bf16_f32 %0, %1, %2" : "=v"(r) : "v"(lo), "v"(hi));
    return r;
}

// single-instruction 2^x
__device__ __forceinline__ float fast_exp2(float x) {
#if __has_builtin(__builtin_amdgcn_exp2f)
    return __builtin_amdgcn_exp2f(x);
#else
    return exp2f(x);
#endif
}

// Exact-GELU via Abramowitz-Stegun 7.1.26 erf (|eps| <= 1.5e-7), branchless.
__device__ __forceinline__ float gelu_exact(float x) {
    float ax = fabsf(x);
    float t  = __builtin_amdgcn_rcpf(fmaf(0.23164193f, ax, 1.0f));
    float poly = fmaf(fmaf(fmaf(fmaf(1.061405429f, t, -1.453152027f),
                               t, 1.421413741f), t, -0.284496736f),
                      t, 0.254829592f) * t;
    float e    = fast_exp2(x * x * -0.72134752f);
    float erfa = fmaf(-poly, e, 1.0f);          // erf(|z|)
    return fmaf(0.5f * ax, erfa, 0.5f * x);
}

// ---------------- kernel 1: fused prep (rms scales + all weight transposes) ----
__global__ __launch_bounds__(256) void prep_kernel(
    const float* __restrict__ x, float* __restrict__ scale,
    const float* __restrict__ w0, const float* __restrict__ w1,
    const float* __restrict__ w2, const float* __restrict__ w3,
    const float* __restrict__ gw,
    unsigned short* __restrict__ wt0, unsigned short* __restrict__ wt1,
    unsigned short* __restrict__ wt2, unsigned short* __restrict__ wt3)
{
    int b = blockIdx.x;
    if (b < 4096) {
        const int lane  = threadIdx.x & 63;
        const int wv    = threadIdx.x >> 6;
        const int token = b * 4 + wv;
        const float* xp = x + (size_t)token * D_TOTAL;
        float s = 0.0f;
#pragma unroll
        for (int j = 0; j < 8; ++j) {
            float4 v = *(const float4*)(xp + (size_t)(j * 64 + lane) * 4);
            s += v.x * v.x + v.y * v.y + v.z * v.z + v.w * v.w;
        }
#pragma unroll
        for (int off = 32; off > 0; off >>= 1) s += __shfl_down(s, off, 64);
        if (lane == 0)
            scale[token] = rsqrtf(s * (1.0f / (float)D_TOTAL) + RMS_EPS);
        return;
    }

    b -= 4096;
    const float* in; unsigned short* out; int K, N; const float* gm = nullptr;
    if      (b <  256) { in = w0; out = wt0; K = 128; N = 512; gm = gw; }
    else if (b < 1280) { in = w1; out = wt1; K = 512; N = 512; b -= 256; }
    else if (b < 2304) { in = w2; out = wt2; K = 512; N = 512; b -= 1280; }
    else               { in = w3; out = wt3; K = 512; N = 128; b -= 2304; }

    const int ktiles = K >> 6, ntiles = N >> 6;
    const int h   = b / (ktiles * ntiles);
    const int rem = b % (ktiles * ntiles);
    const int kt  = rem / ntiles, nt = rem % ntiles;

    const float* src = in + (size_t)h * K * N + (size_t)(kt * 64) * N + nt * 64;
    unsigned short* dst = out + (size_t)h * N * K + (size_t)(nt * 64) * K + kt * 64;

    __shared__ unsigned short tile[64][72];

#pragma unroll
    for (int p = 0; p < 2; ++p) {
        int gi = threadIdx.x + p * 256;
        int r  = gi >> 3;
        int gc = (gi & 7) * 8;
        float mul = 1.0f;
        if (gm) mul = gm[(size_t)h * K + kt * 64 + r];
        float4 a  = *(const float4*)(src + (size_t)r * N + gc);
        float4 b4 = *(const float4*)(src + (size_t)r * N + gc + 4);
        unsigned short tmp[8];
        tmp[0]=f2bf(a.x*mul);  tmp[1]=f2bf(a.y*mul);  tmp[2]=f2bf(a.z*mul);  tmp[3]=f2bf(a.w*mul);
        tmp[4]=f2bf(b4.x*mul); tmp[5]=f2bf(b4.y*mul); tmp[6]=f2bf(b4.z*mul); tmp[7]=f2bf(b4.w*mul);
        *(uint4*)&tile[r][gc] = *(const uint4*)tmp;
    }
    __syncthreads();
#pragma unroll
    for (int p = 0; p < 2; ++p) {
        int gi  = threadIdx.x + p * 256;
        int r2  = gi >> 3;
        int gc2 = (gi & 7) * 8;
        unsigned short tmp[8];
#pragma unroll
        for (int j = 0; j < 8; ++j) tmp[j] = tile[gc2 + j][r2];
        *(uint4*)(dst + (size_t)r2 * K + gc2) = *(const uint4*)tmp;
    }
}

// ---------------- epilogue group: 4 gelu + 2 cvt_pk + one 8B swizzled write ----
// Swapped-D 32x32 layout: lane holds token = mt*32+(l&31), n = nb+nt*32+8g+4h+i.
// gi (0..15) -> mt = gi>>3, nt = (gi>>2)&1, g = gi&3.
__device__ __forceinline__ void epi_group(
    unsigned short* __restrict__ sH, int lane, const f32x16 (&acc)[2][2],
    int nbase, int gi)
{
    const int r31 = lane & 31;
    const int h   = lane >> 5;
    const int mt  = gi >> 3, nt = (gi >> 2) & 1, g = gi & 3;
    const int tok = mt * 32 + r31;
    const int col = nbase + nt * 32 + 8 * g + 4 * h;
    float g0 = gelu_exact(acc[mt][nt][4 * g + 0]);
    float g1 = gelu_exact(acc[mt][nt][4 * g + 1]);
    float g2 = gelu_exact(acc[mt][nt][4 * g + 2]);
    float g3 = gelu_exact(acc[mt][nt][4 * g + 3]);
    uint2_t v;
    v.x = cvt_pk_bf16(g0, g1);
    v.y = cvt_pk_bf16(g2, g3);
    const int gsw = (col >> 3) ^ (tok & 7);
    *(uint2_t*)&sH[(unsigned)tok * HID + gsw * 8 + (col & 7)] = v;
}

// ---------------- stage-0 chunk: normalized x (bf16) into cols [0,128) -------
// 64 rows x 16 granules = 1024 granules; 512 threads -> chunk c in {0,1}.
__device__ __forceinline__ void stage0_chunk(
    const float* __restrict__ x, const float* __restrict__ scale,
    unsigned short* __restrict__ sH, int head, int tokbase, int tid, int c)
{
    int gi = tid + c * 512;
    int r  = gi >> 4;
    int gc = gi & 15;
    int token = tokbase + r;
    const float* xp = x + (size_t)token * D_TOTAL + head * D_HEAD + gc * 8;
    float4 xa = *(const float4*)(xp);
    float4 xb = *(const float4*)(xp + 4);
    float s = scale[token];
    unsigned int u[4];
    u[0] = cvt_pk_bf16(xa.x * s, xa.y * s);
    u[1] = cvt_pk_bf16(xa.z * s, xa.w * s);
    u[2] = cvt_pk_bf16(xb.x * s, xb.y * s);
    u[3] = cvt_pk_bf16(xb.z * s, xb.w * s);
    int gsw = gc ^ (r & 7);
    *(uint4*)&sH[r * HID + gsw * 8] = *(const uint4*)u;
}

// ---------------- fused chain GEMM stage (operand-swapped, 32x32x16) --------
// Per-kstep callback cb(ks) lets the caller interleave the OTHER half's
// epilogue VALU (or stage-0 loads) into this K-loop's MFMA shadow.
template<int K, int MTT, int NT, class CB>
__device__ __forceinline__ void stage_gemm32(
    const unsigned short* __restrict__ sA,      // LDS half, 64 x 512 bf16, swizzled
    const unsigned short* __restrict__ wt,      // global bf16, [N][K] this head
    int lane, int mt0, int nbase, f32x16 acc[MTT][NT], CB&& cb)
{
    constexpr int NK = K / 16;
#pragma unroll
    for (int mt = 0; mt < MTT; ++mt)
#pragma unroll
        for (int nt = 0; nt < NT; ++nt)
#pragma unroll
            for (int i = 0; i < 16; ++i) acc[mt][nt][i] = 0.0f;

    const int r31 = lane & 31;
    const int h   = lane >> 5;            // 0/1: k-half selector

    const char* arow[NT];
#pragma unroll
    for (int nt = 0; nt < NT; ++nt)
        arow[nt] = (const char*)(wt + (size_t)(nbase + nt * 32 + r31) * K + h * 8);

    // B (activation) swizzled byte-address bases: addr(ks) = vb ^ (ks<<5)
    const char* sab = (const char*)sA;
    unsigned int vb[MTT];
#pragma unroll
    for (int mt = 0; mt < MTT; ++mt) {
        unsigned int row = (unsigned)(mt0 + mt * 32 + r31);
        unsigned int r7  = row & 7u;
        unsigned int g0  = (r7 & 6u) | ((unsigned)h ^ (r7 & 1u));
        vb[mt] = row * 1024u + (g0 << 4);
    }

    // depth-2 A prefetch
    short8 apf[2][NT];
#pragma unroll
    for (int nt = 0; nt < NT; ++nt) apf[0][nt] = *(const short8*)(arow[nt]);
#pragma unroll
    for (int nt = 0; nt < NT; ++nt) apf[1][nt] = *(const short8*)(arow[nt] + 32);

#pragma unroll
    for (int ks = 0; ks < NK; ++ks) {
        short8 a[NT];
#pragma unroll
        for (int nt = 0; nt < NT; ++nt) a[nt] = apf[ks & 1][nt];
        if (ks + 2 < NK) {
#pragma unroll
            for (int nt = 0; nt < NT; ++nt)
                apf[ks & 1][nt] = *(const short8*)(arow[nt] + (ks + 2) * 32);
        }
        short8 b[MTT];
#pragma unroll
        for (int mt = 0; mt < MTT; ++mt)
            b[mt] = *(const short8*)(sab + (vb[mt] ^ (unsigned)(ks << 5)));
        cb(ks);                            // other-half epilogue / stage-0 work
#pragma unroll
        for (int mt = 0; mt < MTT; ++mt)
#pragma unroll
            for (int nt = 0; nt < NT; ++nt)
                acc[mt][nt] = __builtin_amdgcn_mfma_f32_32x32x16_bf16(
                    a[nt], b[mt], acc[mt][nt], 0, 0, 0);
    }
}

// ---------------- kernel 3: fused per-(head, token-tile) chain ----------------
// Two 64-token halves A/B software-pipelined: every barrier-to-barrier phase
// pairs half-X's K-loop (MFMA) with half-Y's epilogue (VALU), the epilogue
// groups distributed one per 2 ksteps inside the unrolled K-loop. MFMA and
// VALU pipes run concurrently within each wave; barriers only separate a
// half's epilogue from ITS next K-loop.
__global__ __launch_bounds__(512, 2) void fused_chain_kernel(
    const float*          __restrict__ x,     // fp32
    const float*          __restrict__ scale,
    const unsigned short* __restrict__ wt0,   // [H][512][128] bf16 (g pre-folded)
    const unsigned short* __restrict__ wt1,   // [H][512][512] bf16
    const unsigned short* __restrict__ wt2,   // [H][512][512] bf16
    const unsigned short* __restrict__ wt3,   // [H][128][512] bf16
    float*                __restrict__ out)   // fp32
{
    __shared__ unsigned short sAct[2][HT * HID];   // 2 x 64 KiB

    const int tid  = threadIdx.x;
    const int lane = tid & 63;
    const int wv   = tid >> 6;            // 0..7
    const int bx    = blockIdx.x;
    const int xcd   = bx & 7;
    const int local = bx >> 3;            // 0..255
    const int head  = xcd * 2 + (local >> 7);
    const int tile  = local & 127;
    const int tok0  = tile * MT;

    unsigned short* sA0 = sAct[0];
    unsigned short* sA1 = sAct[1];
    const unsigned short* w0h = wt0 + (size_t)head * HID * D_HEAD;
    const unsigned short* w1h = wt1 + (size_t)head * HID * HID;
    const unsigned short* w2h = wt2 + (size_t)head * HID * HID;
    const unsigned short* w3h = wt3 + (size_t)head * D_HEAD * HID;

    f32x16 accA[2][2], accB[2][2];
    const int nb = wv * 64;              // this wave's N-chunk for stages 1-3

    // ---- step 0: stage0(A) ----
    stage0_chunk(x, scale, sA0, head, tok0, tid, 0);
    stage0_chunk(x, scale, sA0, head, tok0, tid, 1);
    __syncthreads();

    // ---- step 1: K(A,1) || stage0(B) ----
    stage_gemm32<128, 2, 2>(sA0, w0h, lane, 0, nb, accA, [&](int ks) {
        if (ks == 2) stage0_chunk(x, scale, sA1, head, tok0 + HT, tid, 0);
        if (ks == 5) stage0_chunk(x, scale, sA1, head, tok0 + HT, tid, 1);
    });
    __syncthreads();

    // ---- step 2: K(B,1) || epi(A,1) ----   (NK=8: 2 groups per kstep)
    stage_gemm32<128, 2, 2>(sA1, w0h, lane, 0, nb, accB, [&](int ks) {
        epi_group(sA0, lane, accA, nb, 2 * ks);
        epi_group(sA0, lane, accA, nb, 2 * ks + 1);
    });
    __syncthreads();

    // ---- step 3: K(A,2) || epi(B,1) ----   (NK=32: 1 group per 2 ksteps)
    stage_gemm32<512, 2, 2>(sA0, w1h, lane, 0, nb, accA, [&](int ks) {
        if (ks & 1) epi_group(sA1, lane, accB, nb, ks >> 1);
    });
    __syncthreads();

    // ---- step 4: K(B,2) || epi(A,2) ----
    stage_gemm32<512, 2, 2>(sA1, w1h, lane, 0, nb, accB, [&](int ks) {
        if (ks & 1) epi_group(sA0, lane, accA, nb, ks >> 1);
    });
    __syncthreads();

    // ---- step 5: K(A,3) || epi(B,2) ----
    stage_gemm32<512, 2, 2>(sA0, w2h, lane, 0, nb, accA, [&](int ks) {
        if (ks & 1) epi_group(sA1, lane, accB, nb, ks >> 1);
    });
    __syncthreads();

    // ---- step 6: K(B,3) || epi(A,3) ----
    stage_gemm32<512, 2, 2>(sA1, w2h, lane, 0, nb, accB, [&](int ks) {
        if (ks & 1) epi_group(sA0, lane, accA, nb, ks >> 1);
    });
    __syncthreads();

    // ---- step 7: K(A,4) || epi(B,3) ----  stage 4: 8 32x32 tiles / 8 waves
    const int mt4 = (wv >> 2) * 32;       // token 32-block within half
    const int nb4 = (wv & 3) * 32;        // col 32-block
    f32x16 acc4[1][1];
    stage_gemm32<512, 1, 1>(sA0, w3h, lane, mt4, nb4, acc4, [&](int ks) {
        if (ks & 1) epi_group(sA1, lane, accB, nb, ks >> 1);
    });

    // store(A): lane holds 4 consecutive output cols for a fixed token
    {
        const int r31 = lane & 31, h = lane >> 5;
        const int token = tok0 + mt4 + r31;
#pragma unroll
        for (int g = 0; g < 4; ++g) {
            const int col = head * D_HEAD + nb4 + 8 * g + 4 * h;
            float4_t v;
            v[0] = acc4[0][0][4 * g + 0];
            v[1] = acc4[0][0][4 * g + 1];
            v[2] = acc4[0][0][4 * g + 2];
            v[3] = acc4[0][0][4 * g + 3];
            *(float4_t*)&out[(size_t)token * D_TOTAL + col] = v;
        }
    }
    __syncthreads();

    // ---- step 8: K(B,4) ----
    stage_gemm32<512, 1, 1>(sA1, w3h, lane, mt4, nb4, acc4, [](int) {});
    {
        const int r31 = lane & 31, h = lane >> 5;
        const int token = tok0 + HT + mt4 + r31;
#pragma unroll
        for (int g = 0; g < 4; ++g) {
            const int col = head * D_HEAD + nb4 + 8 * g + 4 * h;
            float4_t v;
            v[0] = acc4[0][0][4 * g + 0];
            v[1] = acc4[0][0][4 * g + 1];
            v[2] = acc4[0][0][4 * g + 2];
            v[3] = acc4[0][0][4 * g + 3];
            *(float4_t*)&out[(size_t)token * D_TOTAL + col] = v;
        }
    }
}

// ---------------- host launcher ----------------
extern "C" void kernel_launch(void* const* d_in, const int* in_sizes, int n_in,
                              void* d_out, int out_size, void* d_ws, size_t ws_size,
                              hipStream_t stream)
{
    const float* x  = (const float*)d_in[0];
    const float* gw = (const float*)d_in[1];
    const float* w0 = (const float*)d_in[2];
    const float* w1 = (const float*)d_in[3];
    const float* w2 = (const float*)d_in[4];
    const float* w3 = (const float*)d_in[5];
    float* out = (float*)d_out;

    // workspace layout
    float* scale = (float*)d_ws;                                   // 64 KB
    unsigned short* wt0 = (unsigned short*)((char*)d_ws + 65536);  // [16][512][128]
    unsigned short* wt1 = wt0 + (size_t)N_HEAD * HID * D_HEAD;     // [16][512][512]
    unsigned short* wt2 = wt1 + (size_t)N_HEAD * HID * HID;        // [16][512][512]
    unsigned short* wt3 = wt2 + (size_t)N_HEAD * HID * HID;        // [16][128][512]

    // one prep launch: rms scales (4096 blocks) + 2560 transpose tiles
    prep_kernel<<<4096 + 2560, 256, 0, stream>>>(
        x, scale, w0, w1, w2, w3, gw, wt0, wt1, wt2, wt3);

    fused_chain_kernel<<<N_HEAD * (N_TOK / MT), 512, 0, stream>>>(
        x, scale, wt0, wt1, wt2, wt3, out);
}